// Round 10
// baseline (243.683 us; speedup 1.0000x reference)
//
#include <hip/hip_runtime.h>
#include <hip/hip_bf16.h>
#include <cstdint>
#include <cstddef>

#define B_  2
#define T_  4096
#define D_  768
#define H_  12
#define HD_ 64
#define M_  (B_*T_)   // 8192 rows

#define SCL 0.18033688f   // (1/sqrt(64)) * log2(e): folded into K projection

typedef __bf16 bf16x8 __attribute__((ext_vector_type(8)));
typedef float  f32x4  __attribute__((ext_vector_type(4)));
using bf16 = __hip_bfloat16;

__device__ inline float fexp2(float x) {
  float r; asm("v_exp_f32 %0, %1" : "=v"(r) : "v"(x)); return r;
}
__device__ inline uint32_t fu(float x) { union { float f; uint32_t u; } c; c.f = x; return c.u; }
__device__ inline uint32_t pktr(float a, float b) {   // truncated bf16 pair, 1 v_perm
  return __builtin_amdgcn_perm(fu(b), fu(a), 0x07060302);
}
#define GLD16(g, l) __builtin_amdgcn_global_load_lds( \
    (const __attribute__((address_space(1))) uint32_t*)(const void*)(g), \
    (__attribute__((address_space(3))) uint32_t*)(void*)(l), 16, 0, 0)

// ---------------- fp32 -> bf16 conversion (x + 4 weights, exact 1D grid) ---------
__global__ void cvt_all(const float* __restrict__ x,
                        const float* __restrict__ w0, const float* __restrict__ w1,
                        const float* __restrict__ w2, const float* __restrict__ w3,
                        bf16* __restrict__ xd,
                        bf16* __restrict__ d0, bf16* __restrict__ d1,
                        bf16* __restrict__ d2, bf16* __restrict__ d3) {
  int blk = blockIdx.x;
  const float* s; bf16* d; int i;
  if (blk < 6144) {                       // x: 6144*256 == M*D/4 exactly
    s = x; d = xd; i = blk * 256 + threadIdx.x;
  } else {                                // weights: 576*256 == D*D/4 exactly
    int q = blk - 6144, which = q / 576, rb = q % 576;
    switch (which) {
      case 0: s = w0; d = d0; break;
      case 1: s = w1; d = d1; break;
      case 2: s = w2; d = d2; break;
      default: s = w3; d = d3; break;
    }
    i = rb * 256 + threadIdx.x;
  }
  float4 v = ((const float4*)s)[i];
  union { bf16 o[4]; uint2 u; } pk;
  pk.o[0] = __float2bfloat16(v.x); pk.o[1] = __float2bfloat16(v.y);
  pk.o[2] = __float2bfloat16(v.z); pk.o[3] = __float2bfloat16(v.w);
  *(uint2*)(d + 4 * (size_t)i) = pk.u;
}

// ---------------- unified QKV GEMM v2: triple-buffer + counted vmcnt -------------
// R9: gemm_qkv is the largest unprofiled block (~60-75us est). The 2-buffer
// __syncthreads loop drains vmcnt(0) each K-step with only 1 compute-phase of
// load-latency cover. v2: 3 LDS buffers, loads issued 2 tiles ahead, barrier =
// asm vmcnt(4) (wait ONLY the oldest tile's 4 loads; keep 4 in flight) + raw
// s_barrier. LDS 48KB -> 3 blocks/CU, 1152 blocks > 768 resident (backfill ok).
__global__ __launch_bounds__(256) void gemm_qkv(const bf16* __restrict__ x,
                                                const bf16* __restrict__ W0,
                                                const bf16* __restrict__ W1,
                                                const bf16* __restrict__ W2,
                                                bf16* __restrict__ O0,
                                                bf16* __restrict__ O1,
                                                bf16* __restrict__ O2t) {
  __shared__ bf16 As[3][4096];
  __shared__ bf16 Bs[3][4096];
  const int flat = blockIdx.x;
  const int by = flat / 18;            // token tile (m)
  const int rr = flat % 18;
  const int z  = rr / 6;
  const int bx = rr % 6;               // feature tile (n)
  const bf16* Wz = (z == 0) ? W0 : ((z == 1) ? W1 : W2);
  const char* Ap; const char* Bp; int a0, b0;
  if (z == 2) { Ap = (const char*)x;  a0 = by * 128; Bp = (const char*)Wz; b0 = bx * 128; }
  else        { Ap = (const char*)Wz; a0 = bx * 128; Bp = (const char*)x;  b0 = by * 128; }
  const int t = threadIdx.x;
  const int w = t >> 6, lane = t & 63;
  const int wa = (w >> 1) * 64, wb = (w & 1) * 64;
  const int mi = lane & 15, qd = lane >> 4;

  int aoff[2], boff[2];
  #pragma unroll
  for (int i = 0; i < 2; ++i) {
    int L = i * 256 + t;
    int row = L >> 2, sl = L & 3, c = sl ^ (row & 3);
    aoff[i] = (a0 + row) * 1536 + c * 16;
    boff[i] = (b0 + row) * 1536 + c * 16;
  }
  const int fsw = (qd ^ (mi & 3)) * 8;

  f32x4 acc[4][4] = {};

  // prologue: tiles 0 and 1 into buffers 0 and 1 (8 loads/thread in flight)
  #pragma unroll
  for (int p = 0; p < 2; ++p)
    #pragma unroll
    for (int i = 0; i < 2; ++i) {
      GLD16(Ap + aoff[i] + p * 64, &As[p][i * 2048 + w * 512]);
      GLD16(Bp + boff[i] + p * 64, &Bs[p][i * 2048 + w * 512]);
    }

  #pragma unroll 3
  for (int kk = 0; kk < 24; ++kk) {
    const int cur = kk % 3;
    // wait only tile kk's 4 loads (oldest); tile kk+1's stay in flight
    if (kk < 23) asm volatile("s_waitcnt vmcnt(4)" ::: "memory");
    else         asm volatile("s_waitcnt vmcnt(0)" ::: "memory");
    __builtin_amdgcn_s_barrier();
    if (kk + 2 < 24) {                 // issue tile kk+2 into the freed buffer
      const int nb = (kk + 2) % 3, kb = (kk + 2) * 64;
      #pragma unroll
      for (int i = 0; i < 2; ++i) {
        GLD16(Ap + aoff[i] + kb, &As[nb][i * 2048 + w * 512]);
        GLD16(Bp + boff[i] + kb, &Bs[nb][i * 2048 + w * 512]);
      }
    }
    bf16x8 af[4], bfr[4];
    #pragma unroll
    for (int at = 0; at < 4; ++at)
      af[at] = *(const bf16x8*)&As[cur][(wa + at * 16 + mi) * 32 + fsw];
    #pragma unroll
    for (int bt = 0; bt < 4; ++bt)
      bfr[bt] = *(const bf16x8*)&Bs[cur][(wb + bt * 16 + mi) * 32 + fsw];
    #pragma unroll
    for (int at = 0; at < 4; ++at)
      #pragma unroll
      for (int bt = 0; bt < 4; ++bt)
        acc[at][bt] = __builtin_amdgcn_mfma_f32_16x16x32_bf16(af[at], bfr[bt], acc[at][bt], 0, 0, 0);
  }

  if (z == 2) {
    #pragma unroll
    for (int at = 0; at < 4; ++at)
      #pragma unroll
      for (int bt = 0; bt < 4; ++bt) {
        int gr = a0 + wa + at * 16 + qd * 4;          // token
        int gc = b0 + wb + bt * 16 + mi;              // feature
        union { bf16 o[4]; uint2 u; } pk;
        #pragma unroll
        for (int r = 0; r < 4; ++r) pk.o[r] = __float2bfloat16(acc[at][bt][r]);
        int bb = gr >> 12, tt = gr & 4095;
        *(uint2*)(O2t + (size_t)bb * 768 * 4096 + (size_t)gc * 4096 + tt) = pk.u;
      }
  } else {
    const float scl = (z == 1) ? SCL : 1.0f;
    bf16* Ob = (z == 0) ? O0 : O1;
    #pragma unroll
    for (int at = 0; at < 4; ++at)
      #pragma unroll
      for (int bt = 0; bt < 4; ++bt) {
        int f0  = a0 + wa + at * 16 + qd * 4;
        int tkn = b0 + wb + bt * 16 + mi;
        union { bf16 o[4]; uint2 u; } pk;
        #pragma unroll
        for (int r = 0; r < 4; ++r) pk.o[r] = __float2bfloat16(acc[at][bt][r] * scl);
        *(uint2*)(Ob + (size_t)tkn * 768 + f0) = pk.u;
      }
  }
}

// ---------------- output projection v3: BN=64 + triple-buffer counted vmcnt ------
// 768 blocks (3/CU); 36KB LDS -> 4 blocks/CU resident cap (no occupancy loss).
// Same counted-wait pattern: 3 loads/tile/thread -> vmcnt(3).
__global__ __launch_bounds__(256) void gemm_out(const bf16* __restrict__ ctx,
                                                const bf16* __restrict__ Wo,
                                                float* __restrict__ Cf,
                                                const float* __restrict__ bias) {
  __shared__ bf16 As[3][2048];
  __shared__ bf16 Bs[3][4096];
  const int flat = blockIdx.x;
  const int by = flat / 12, bx = flat % 12;
  const char* Ap = (const char*)Wo;  const int a0 = bx * 64;    // feature rows
  const char* Bp = (const char*)ctx; const int b0 = by * 128;   // token rows
  const int t = threadIdx.x;
  const int w = t >> 6, lane = t & 63;
  const int wa = (w >> 1) * 32, wb = (w & 1) * 64;
  const int mi = lane & 15, qd = lane >> 4;

  int aoff, boff[2];
  { int row = t >> 2, sl = t & 3, c = sl ^ (row & 3);
    aoff = (a0 + row) * 1536 + c * 16; }
  #pragma unroll
  for (int i = 0; i < 2; ++i) {
    int L = i * 256 + t;
    int row = L >> 2, sl = L & 3, c = sl ^ (row & 3);
    boff[i] = (b0 + row) * 1536 + c * 16;
  }
  const int fsw = (qd ^ (mi & 3)) * 8;

  f32x4 acc[2][4] = {};

  #pragma unroll
  for (int p = 0; p < 2; ++p) {
    GLD16(Ap + aoff + p * 64, &As[p][w * 512]);
    #pragma unroll
    for (int i = 0; i < 2; ++i)
      GLD16(Bp + boff[i] + p * 64, &Bs[p][i * 2048 + w * 512]);
  }

  #pragma unroll 3
  for (int kk = 0; kk < 24; ++kk) {
    const int cur = kk % 3;
    if (kk < 23) asm volatile("s_waitcnt vmcnt(3)" ::: "memory");
    else         asm volatile("s_waitcnt vmcnt(0)" ::: "memory");
    __builtin_amdgcn_s_barrier();
    if (kk + 2 < 24) {
      const int nb = (kk + 2) % 3, kb = (kk + 2) * 64;
      GLD16(Ap + aoff + kb, &As[nb][w * 512]);
      #pragma unroll
      for (int i = 0; i < 2; ++i)
        GLD16(Bp + boff[i] + kb, &Bs[nb][i * 2048 + w * 512]);
    }
    bf16x8 af[2], bfr[4];
    #pragma unroll
    for (int at = 0; at < 2; ++at)
      af[at] = *(const bf16x8*)&As[cur][(wa + at * 16 + mi) * 32 + fsw];
    #pragma unroll
    for (int bt = 0; bt < 4; ++bt)
      bfr[bt] = *(const bf16x8*)&Bs[cur][(wb + bt * 16 + mi) * 32 + fsw];
    #pragma unroll
    for (int at = 0; at < 2; ++at)
      #pragma unroll
      for (int bt = 0; bt < 4; ++bt)
        acc[at][bt] = __builtin_amdgcn_mfma_f32_16x16x32_bf16(af[at], bfr[bt], acc[at][bt], 0, 0, 0);
  }

  #pragma unroll
  for (int at = 0; at < 2; ++at)
    #pragma unroll
    for (int bt = 0; bt < 4; ++bt) {
      int f0  = a0 + wa + at * 16 + qd * 4;
      int tkn = b0 + wb + bt * 16 + mi;
      float4 bv = *(const float4*)&bias[f0];
      float4 o;
      o.x = acc[at][bt][0] + bv.x; o.y = acc[at][bt][1] + bv.y;
      o.z = acc[at][bt][2] + bv.z; o.w = acc[at][bt][3] + bv.w;
      *(float4*)&Cf[(size_t)tkn * 768 + f0] = o;
    }
}

// ---------------- MFMA flash attention v11 (reverted best: 75.3us) ---------------
// v13 (j-split) measured 80.4us with scratch/extra-HBM signature -> reverted.
// v11: 64-row blocks, grid 1536 (backfill), permuted-K staging, K=32 PV.
__global__ __launch_bounds__(256, 5) void flash_attn(const bf16* __restrict__ Q,
                                                     const bf16* __restrict__ K,
                                                     const bf16* __restrict__ Vt,
                                                     bf16* __restrict__ ctx) {
  __shared__ bf16 Ks[2][4096];
  __shared__ bf16 Vs[2][4096];
  const int t = threadIdx.x;
  const int w = t >> 6, lane = t & 63;
  const int mi = lane & 15, qd = lane >> 4;
  const int bh   = blockIdx.x % 24;
  const int qrev = blockIdx.x / 24;          // heavy blocks (large q0) first
  const int q0 = T_ - 64 - qrev * 64;
  const int b = bh / H_, h = bh % H_;
  const size_t bTD = (size_t)b * T_ * D_;
  const char* Kp = (const char*)(K  + bTD + (size_t)h * HD_);
  const char* Vp = (const char*)(Vt + (size_t)b * D_ * T_ + (size_t)h * HD_ * T_);
  const int qw = q0 + w * 16;                // wave's 16 q-rows

  // staging: 256 threads x 2 chunks x 16B = full 64x64 tile per buffer.
  // K global row permuted: LDS row rl <- key jrow = 32*b5 + 8*(b3b2) + 4*b4 + b1b0
  int vkoff[2], vvoff[2];
  #pragma unroll
  for (int i = 0; i < 2; ++i) {
    int L = i * 256 + t;
    int rl = L >> 3, c = (L & 7) ^ (rl & 7);
    int jrow = (rl & 32) | ((rl & 0xC) << 1) | ((rl & 16) >> 2) | (rl & 3);
    vkoff[i] = jrow * 1536 + c * 16;
    vvoff[i] = rl * 8192 + c * 16;
  }

  // b128 reads (K as QK A-op, V as PV A-op): row = jt*16+mi, granule (kt*4+qd)^(mi&7)
  int fidx[4][2];
  #pragma unroll
  for (int jt = 0; jt < 4; ++jt)
    #pragma unroll
    for (int kt = 0; kt < 2; ++kt)
      fidx[jt][kt] = (jt * 16 + mi) * 64 + (((kt * 4 + qd) ^ (mi & 7)) * 8);

  bf16x8 qf[2];
  const bf16* Qp = Q + bTD + (size_t)h * HD_;
  #pragma unroll
  for (int kt = 0; kt < 2; ++kt)
    qf[kt] = *(const bf16x8*)(Qp + (size_t)(qw + mi) * D_ + kt * 32 + qd * 8);

  f32x4 oacc[4] = {};
  float lst = 0.f;
  const int ntiles = q0 / 64 + 1;

  #pragma unroll
  for (int i = 0; i < 2; ++i) {
    GLD16(Kp + vkoff[i], &Ks[0][i * 2048 + w * 512]);
    GLD16(Vp + vvoff[i], &Vs[0][i * 2048 + w * 512]);
  }

  for (int tt = 0; tt < ntiles; ++tt) {
    __syncthreads();
    const int par = tt & 1;
    if (tt + 1 < ntiles) {
      const size_t j1 = (size_t)(tt + 1) * 64;
      const int np = par ^ 1;
      #pragma unroll
      for (int i = 0; i < 2; ++i) {
        GLD16(Kp + vkoff[i] + j1 * 1536, &Ks[np][i * 2048 + w * 512]);
        GLD16(Vp + vvoff[i] + j1 * 2,    &Vs[np][i * 2048 + w * 512]);
      }
    }
    const int j0 = tt * 64;
    if (j0 > qw + 15) continue;               // fully masked for this wave

    // S^T = K-tile @ Q^T  (C row m=4qd+r of subtile jt holds key
    // j = 32(jt>>1) + 8qd + 4(jt&1) + r due to permuted staging)
    f32x4 sacc[4] = {};
    __builtin_amdgcn_s_setprio(1);
    #pragma unroll
    for (int jt = 0; jt < 4; ++jt)
      #pragma unroll
      for (int kt = 0; kt < 2; ++kt) {
        bf16x8 kf = *(const bf16x8*)&Ks[par][fidx[jt][kt]];
        sacc[jt] = __builtin_amdgcn_mfma_f32_16x16x32_bf16(kf, qf[kt], sacc[jt], 0, 0, 0);
      }
    __builtin_amdgcn_s_setprio(0);

    if (j0 + 63 > qw) {                       // causal mask, diagonal tile only
      const int qg = qw + mi;
      #pragma unroll
      for (int jt = 0; jt < 4; ++jt)
        #pragma unroll
        for (int r = 0; r < 4; ++r) {
          int jg = j0 + ((jt >> 1) << 5) + (qd << 3) + ((jt & 1) << 2) + r;
          if (jg > qg) sacc[jt][r] = -1e30f;
        }
    }

    // p = exp2(s); per-lane partial l; pack: lane holds keys 32kt+8qd+0..7
    // = the K=32 B-operand fragment, keys in natural order.
    uint32_t pu[4][2];
    #pragma unroll
    for (int jt = 0; jt < 4; ++jt) {
      float p0 = fexp2(sacc[jt][0]);
      float p1 = fexp2(sacc[jt][1]);
      float p2 = fexp2(sacc[jt][2]);
      float p3 = fexp2(sacc[jt][3]);
      lst += (p0 + p1) + (p2 + p3);
      pu[jt][0] = pktr(p0, p1);
      pu[jt][1] = pktr(p2, p3);
    }
    bf16x8 pB[2];
    #pragma unroll
    for (int kt = 0; kt < 2; ++kt) {
      union { uint32_t u[4]; bf16x8 v; } m;
      m.u[0] = pu[2 * kt][0];     m.u[1] = pu[2 * kt][1];
      m.u[2] = pu[2 * kt + 1][0]; m.u[3] = pu[2 * kt + 1][1];
      pB[kt] = m.v;
    }

    // O^T += V^T @ P^T via K=32 MFMA (V b128 reads, same pattern as K reads)
    __builtin_amdgcn_s_setprio(1);
    #pragma unroll
    for (int kt = 0; kt < 2; ++kt)
      #pragma unroll
      for (int dt = 0; dt < 4; ++dt) {
        bf16x8 vf = *(const bf16x8*)&Vs[par][fidx[dt][kt]];
        oacc[dt] = __builtin_amdgcn_mfma_f32_16x16x32_bf16(vf, pB[kt], oacc[dt], 0, 0, 0);
      }
    __builtin_amdgcn_s_setprio(0);
  }

  // epilogue: finish l across quads, normalize, packed uint2 stores
  float l = lst;
  l += __shfl_xor(l, 16);
  l += __shfl_xor(l, 32);
  float inv = __builtin_amdgcn_rcpf(l);
  const int qg = qw + mi;
  bf16* cp = ctx + bTD + (size_t)qg * D_ + h * HD_ + qd * 4;
  #pragma unroll
  for (int dt = 0; dt < 4; ++dt) {
    union { bf16 o[4]; uint2 u; } pko;
    #pragma unroll
    for (int r = 0; r < 4; ++r) pko.o[r] = __float2bfloat16(oacc[dt][r] * inv);
    *(uint2*)(cp + dt * 16) = pko.u;
  }
}

// ---------------- launch ----------------
extern "C" void kernel_launch(void* const* d_in, const int* in_sizes, int n_in,
                              void* d_out, int out_size, void* d_ws, size_t ws_size,
                              hipStream_t stream) {
  const float* x  = (const float*)d_in[0];
  const float* Wq = (const float*)d_in[1];
  const float* Wk = (const float*)d_in[2];
  const float* Wv = (const float*)d_in[3];
  const float* Wo = (const float*)d_in[4];
  const float* bo = (const float*)d_in[5];
  float* out = (float*)d_out;

  char* ws = (char*)d_ws;
  const size_t SZ  = (size_t)M_ * D_ * 2;
  const size_t WSZ = (size_t)D_ * D_ * 2;
  bf16* xb   = (bf16*)(ws);                 // [M, D]
  bf16* Qb   = (bf16*)(ws + 1 * SZ);        // [B,T,D]
  bf16* Kb   = (bf16*)(ws + 2 * SZ);        // [B,T,D], pre-scaled by SCL
  bf16* Vtg  = (bf16*)(ws + 3 * SZ);        // [B][D][T]
  bf16* ctxb = (bf16*)(ws + 4 * SZ);        // [B,T,D]
  bf16* Wqb  = (bf16*)(ws + 5 * SZ);
  bf16* Wkb  = (bf16*)(ws + 5 * SZ + 1 * WSZ);
  bf16* Wvb  = (bf16*)(ws + 5 * SZ + 2 * WSZ);
  bf16* Wob  = (bf16*)(ws + 5 * SZ + 3 * WSZ);

  cvt_all<<<6144 + 4 * 576, 256, 0, stream>>>(x, Wq, Wk, Wv, Wo, xb, Wqb, Wkb, Wvb, Wob);

  gemm_qkv<<<1152, 256, 0, stream>>>(xb, Wqb, Wkb, Wvb, Qb, Kb, Vtg);

  flash_attn<<<(T_ / 64) * B_ * H_, 256, 0, stream>>>(Qb, Kb, Vtg, ctxb);

  gemm_out<<<768, 256, 0, stream>>>(ctxb, Wob, out, bo);
}

// Round 11
// 231.842 us; speedup vs baseline: 1.0511x; 1.0511x over previous
//
#include <hip/hip_runtime.h>
#include <hip/hip_bf16.h>
#include <cstdint>
#include <cstddef>

#define B_  2
#define T_  4096
#define D_  768
#define H_  12
#define HD_ 64
#define M_  (B_*T_)   // 8192 rows

#define SCL 0.18033688f   // (1/sqrt(64)) * log2(e): folded into K projection

typedef __bf16 bf16x8 __attribute__((ext_vector_type(8)));
typedef float  f32x4  __attribute__((ext_vector_type(4)));
using bf16 = __hip_bfloat16;

__device__ inline float fexp2(float x) {
  float r; asm("v_exp_f32 %0, %1" : "=v"(r) : "v"(x)); return r;
}
__device__ inline uint32_t fu(float x) { union { float f; uint32_t u; } c; c.f = x; return c.u; }
__device__ inline uint32_t pktr(float a, float b) {   // truncated bf16 pair, 1 v_perm
  return __builtin_amdgcn_perm(fu(b), fu(a), 0x07060302);
}
#define GLD16(g, l) __builtin_amdgcn_global_load_lds( \
    (const __attribute__((address_space(1))) uint32_t*)(const void*)(g), \
    (__attribute__((address_space(3))) uint32_t*)(void*)(l), 16, 0, 0)

// ---------------- fp32 -> bf16 conversion (x + 4 weights, exact 1D grid) ---------
__global__ void cvt_all(const float* __restrict__ x,
                        const float* __restrict__ w0, const float* __restrict__ w1,
                        const float* __restrict__ w2, const float* __restrict__ w3,
                        bf16* __restrict__ xd,
                        bf16* __restrict__ d0, bf16* __restrict__ d1,
                        bf16* __restrict__ d2, bf16* __restrict__ d3) {
  int blk = blockIdx.x;
  const float* s; bf16* d; int i;
  if (blk < 6144) {                       // x: 6144*256 == M*D/4 exactly
    s = x; d = xd; i = blk * 256 + threadIdx.x;
  } else {                                // weights: 576*256 == D*D/4 exactly
    int q = blk - 6144, which = q / 576, rb = q % 576;
    switch (which) {
      case 0: s = w0; d = d0; break;
      case 1: s = w1; d = d1; break;
      case 2: s = w2; d = d2; break;
      default: s = w3; d = d3; break;
    }
    i = rb * 256 + threadIdx.x;
  }
  float4 v = ((const float4*)s)[i];
  union { bf16 o[4]; uint2 u; } pk;
  pk.o[0] = __float2bfloat16(v.x); pk.o[1] = __float2bfloat16(v.y);
  pk.o[2] = __float2bfloat16(v.z); pk.o[3] = __float2bfloat16(v.w);
  *(uint2*)(d + 4 * (size_t)i) = pk.u;
}

// ---------------- unified QKV GEMM (R6 2-buffer form) + XCD swizzle --------------
// R10 lesson: triple-buffer+counted-vmcnt regressed (~13us; occupancy 5->3
// blocks/CU + compiler already fine-schedules). Reverted to 2-buffer.
// NEW: bijective XCD swizzle. HW round-robins consecutive blockIdx across the 8
// XCDs, so the 18 blocks sharing an x-panel were spread over ALL XCDs -> each
// per-XCD L2 refetched x (up to 8x of 12.6MB). swz gives each XCD a contiguous
// chunk (8 by-tiles x 18): x panels 1.6MB + all W 3.5MB per XCD, mostly L2-hit.
__global__ __launch_bounds__(256) void gemm_qkv(const bf16* __restrict__ x,
                                                const bf16* __restrict__ W0,
                                                const bf16* __restrict__ W1,
                                                const bf16* __restrict__ W2,
                                                bf16* __restrict__ O0,
                                                bf16* __restrict__ O1,
                                                bf16* __restrict__ O2t) {
  __shared__ bf16 As[2][4096];
  __shared__ bf16 Bs[2][4096];
  const int bid  = blockIdx.x;
  const int flat = (bid & 7) * 144 + (bid >> 3);   // 1152 = 8 * 144, bijective
  const int by = flat / 18;            // token tile (m)
  const int rr = flat % 18;
  const int z  = rr / 6;
  const int bx = rr % 6;               // feature tile (n)
  const bf16* Wz = (z == 0) ? W0 : ((z == 1) ? W1 : W2);
  const char* Ap; const char* Bp; int a0, b0;
  if (z == 2) { Ap = (const char*)x;  a0 = by * 128; Bp = (const char*)Wz; b0 = bx * 128; }
  else        { Ap = (const char*)Wz; a0 = bx * 128; Bp = (const char*)x;  b0 = by * 128; }
  const int t = threadIdx.x;
  const int w = t >> 6, lane = t & 63;
  const int wa = (w >> 1) * 64, wb = (w & 1) * 64;
  const int mi = lane & 15, qd = lane >> 4;

  int aoff[2], boff[2];
  #pragma unroll
  for (int i = 0; i < 2; ++i) {
    int L = i * 256 + t;
    int row = L >> 2, sl = L & 3, c = sl ^ (row & 3);
    aoff[i] = (a0 + row) * 1536 + c * 16;
    boff[i] = (b0 + row) * 1536 + c * 16;
  }
  const int fsw = (qd ^ (mi & 3)) * 8;

  f32x4 acc[4][4] = {};

  #pragma unroll
  for (int i = 0; i < 2; ++i) {
    GLD16(Ap + aoff[i], &As[0][i * 2048 + w * 512]);
    GLD16(Bp + boff[i], &Bs[0][i * 2048 + w * 512]);
  }

  for (int kk = 0; kk < 24; ++kk) {
    __syncthreads();
    const int par = kk & 1;
    if (kk + 1 < 24) {
      const int np = par ^ 1, kb = (kk + 1) * 64;
      #pragma unroll
      for (int i = 0; i < 2; ++i) {
        GLD16(Ap + aoff[i] + kb, &As[np][i * 2048 + w * 512]);
        GLD16(Bp + boff[i] + kb, &Bs[np][i * 2048 + w * 512]);
      }
    }
    bf16x8 af[4], bfr[4];
    #pragma unroll
    for (int at = 0; at < 4; ++at)
      af[at] = *(const bf16x8*)&As[par][(wa + at * 16 + mi) * 32 + fsw];
    #pragma unroll
    for (int bt = 0; bt < 4; ++bt)
      bfr[bt] = *(const bf16x8*)&Bs[par][(wb + bt * 16 + mi) * 32 + fsw];
    #pragma unroll
    for (int at = 0; at < 4; ++at)
      #pragma unroll
      for (int bt = 0; bt < 4; ++bt)
        acc[at][bt] = __builtin_amdgcn_mfma_f32_16x16x32_bf16(af[at], bfr[bt], acc[at][bt], 0, 0, 0);
  }

  if (z == 2) {
    #pragma unroll
    for (int at = 0; at < 4; ++at)
      #pragma unroll
      for (int bt = 0; bt < 4; ++bt) {
        int gr = a0 + wa + at * 16 + qd * 4;          // token
        int gc = b0 + wb + bt * 16 + mi;              // feature
        union { bf16 o[4]; uint2 u; } pk;
        #pragma unroll
        for (int r = 0; r < 4; ++r) pk.o[r] = __float2bfloat16(acc[at][bt][r]);
        int bb = gr >> 12, tt = gr & 4095;
        *(uint2*)(O2t + (size_t)bb * 768 * 4096 + (size_t)gc * 4096 + tt) = pk.u;
      }
  } else {
    const float scl = (z == 1) ? SCL : 1.0f;
    bf16* Ob = (z == 0) ? O0 : O1;
    #pragma unroll
    for (int at = 0; at < 4; ++at)
      #pragma unroll
      for (int bt = 0; bt < 4; ++bt) {
        int f0  = a0 + wa + at * 16 + qd * 4;
        int tkn = b0 + wb + bt * 16 + mi;
        union { bf16 o[4]; uint2 u; } pk;
        #pragma unroll
        for (int r = 0; r < 4; ++r) pk.o[r] = __float2bfloat16(acc[at][bt][r] * scl);
        *(uint2*)(Ob + (size_t)tkn * 768 + f0) = pk.u;
      }
  }
}

// ---------------- output projection (R6 BN=64 2-buffer form) + XCD swizzle -------
// 768 blocks (3/CU). Swizzle: each XCD gets 8 by-tiles x 12 bx -> Wo 1.2MB +
// ctx panels 1.6MB < 4MB L2.
__global__ __launch_bounds__(256) void gemm_out(const bf16* __restrict__ ctx,
                                                const bf16* __restrict__ Wo,
                                                float* __restrict__ Cf,
                                                const float* __restrict__ bias) {
  __shared__ bf16 As[2][2048];
  __shared__ bf16 Bs[2][4096];
  const int bid  = blockIdx.x;
  const int flat = (bid & 7) * 96 + (bid >> 3);    // 768 = 8 * 96, bijective
  const int by = flat / 12, bx = flat % 12;
  const char* Ap = (const char*)Wo;  const int a0 = bx * 64;    // feature rows
  const char* Bp = (const char*)ctx; const int b0 = by * 128;   // token rows
  const int t = threadIdx.x;
  const int w = t >> 6, lane = t & 63;
  const int wa = (w >> 1) * 32, wb = (w & 1) * 64;
  const int mi = lane & 15, qd = lane >> 4;

  int aoff, boff[2];
  { int row = t >> 2, sl = t & 3, c = sl ^ (row & 3);
    aoff = (a0 + row) * 1536 + c * 16; }
  #pragma unroll
  for (int i = 0; i < 2; ++i) {
    int L = i * 256 + t;
    int row = L >> 2, sl = L & 3, c = sl ^ (row & 3);
    boff[i] = (b0 + row) * 1536 + c * 16;
  }
  const int fsw = (qd ^ (mi & 3)) * 8;

  f32x4 acc[2][4] = {};

  GLD16(Ap + aoff, &As[0][w * 512]);
  #pragma unroll
  for (int i = 0; i < 2; ++i)
    GLD16(Bp + boff[i], &Bs[0][i * 2048 + w * 512]);

  for (int kk = 0; kk < 24; ++kk) {
    __syncthreads();
    const int par = kk & 1;
    if (kk + 1 < 24) {
      const int np = par ^ 1, kb = (kk + 1) * 64;
      GLD16(Ap + aoff + kb, &As[np][w * 512]);
      #pragma unroll
      for (int i = 0; i < 2; ++i)
        GLD16(Bp + boff[i] + kb, &Bs[np][i * 2048 + w * 512]);
    }
    bf16x8 af[2], bfr[4];
    #pragma unroll
    for (int at = 0; at < 2; ++at)
      af[at] = *(const bf16x8*)&As[par][(wa + at * 16 + mi) * 32 + fsw];
    #pragma unroll
    for (int bt = 0; bt < 4; ++bt)
      bfr[bt] = *(const bf16x8*)&Bs[par][(wb + bt * 16 + mi) * 32 + fsw];
    #pragma unroll
    for (int at = 0; at < 2; ++at)
      #pragma unroll
      for (int bt = 0; bt < 4; ++bt)
        acc[at][bt] = __builtin_amdgcn_mfma_f32_16x16x32_bf16(af[at], bfr[bt], acc[at][bt], 0, 0, 0);
  }

  #pragma unroll
  for (int at = 0; at < 2; ++at)
    #pragma unroll
    for (int bt = 0; bt < 4; ++bt) {
      int f0  = a0 + wa + at * 16 + qd * 4;
      int tkn = b0 + wb + bt * 16 + mi;
      float4 bv = *(const float4*)&bias[f0];
      float4 o;
      o.x = acc[at][bt][0] + bv.x; o.y = acc[at][bt][1] + bv.y;
      o.z = acc[at][bt][2] + bv.z; o.w = acc[at][bt][3] + bv.w;
      *(float4*)&Cf[(size_t)tkn * 768 + f0] = o;
    }
}

// ---------------- MFMA flash attention v11 (best: ~72-75us) ----------------------
// 64-row blocks, grid 1536 (backfill), permuted-K staging, K=32 PV.
// Same-KV blocks already co-located per XCD (stride 24 == 0 mod 8) -> no swizzle.
__global__ __launch_bounds__(256, 5) void flash_attn(const bf16* __restrict__ Q,
                                                     const bf16* __restrict__ K,
                                                     const bf16* __restrict__ Vt,
                                                     bf16* __restrict__ ctx) {
  __shared__ bf16 Ks[2][4096];
  __shared__ bf16 Vs[2][4096];
  const int t = threadIdx.x;
  const int w = t >> 6, lane = t & 63;
  const int mi = lane & 15, qd = lane >> 4;
  const int bh   = blockIdx.x % 24;
  const int qrev = blockIdx.x / 24;          // heavy blocks (large q0) first
  const int q0 = T_ - 64 - qrev * 64;
  const int b = bh / H_, h = bh % H_;
  const size_t bTD = (size_t)b * T_ * D_;
  const char* Kp = (const char*)(K  + bTD + (size_t)h * HD_);
  const char* Vp = (const char*)(Vt + (size_t)b * D_ * T_ + (size_t)h * HD_ * T_);
  const int qw = q0 + w * 16;                // wave's 16 q-rows

  // staging: 256 threads x 2 chunks x 16B = full 64x64 tile per buffer.
  // K global row permuted: LDS row rl <- key jrow = 32*b5 + 8*(b3b2) + 4*b4 + b1b0
  int vkoff[2], vvoff[2];
  #pragma unroll
  for (int i = 0; i < 2; ++i) {
    int L = i * 256 + t;
    int rl = L >> 3, c = (L & 7) ^ (rl & 7);
    int jrow = (rl & 32) | ((rl & 0xC) << 1) | ((rl & 16) >> 2) | (rl & 3);
    vkoff[i] = jrow * 1536 + c * 16;
    vvoff[i] = rl * 8192 + c * 16;
  }

  // b128 reads (K as QK A-op, V as PV A-op): row = jt*16+mi, granule (kt*4+qd)^(mi&7)
  int fidx[4][2];
  #pragma unroll
  for (int jt = 0; jt < 4; ++jt)
    #pragma unroll
    for (int kt = 0; kt < 2; ++kt)
      fidx[jt][kt] = (jt * 16 + mi) * 64 + (((kt * 4 + qd) ^ (mi & 7)) * 8);

  bf16x8 qf[2];
  const bf16* Qp = Q + bTD + (size_t)h * HD_;
  #pragma unroll
  for (int kt = 0; kt < 2; ++kt)
    qf[kt] = *(const bf16x8*)(Qp + (size_t)(qw + mi) * D_ + kt * 32 + qd * 8);

  f32x4 oacc[4] = {};
  float lst = 0.f;
  const int ntiles = q0 / 64 + 1;

  #pragma unroll
  for (int i = 0; i < 2; ++i) {
    GLD16(Kp + vkoff[i], &Ks[0][i * 2048 + w * 512]);
    GLD16(Vp + vvoff[i], &Vs[0][i * 2048 + w * 512]);
  }

  for (int tt = 0; tt < ntiles; ++tt) {
    __syncthreads();
    const int par = tt & 1;
    if (tt + 1 < ntiles) {
      const size_t j1 = (size_t)(tt + 1) * 64;
      const int np = par ^ 1;
      #pragma unroll
      for (int i = 0; i < 2; ++i) {
        GLD16(Kp + vkoff[i] + j1 * 1536, &Ks[np][i * 2048 + w * 512]);
        GLD16(Vp + vvoff[i] + j1 * 2,    &Vs[np][i * 2048 + w * 512]);
      }
    }
    const int j0 = tt * 64;
    if (j0 > qw + 15) continue;               // fully masked for this wave

    // S^T = K-tile @ Q^T  (C row m=4qd+r of subtile jt holds key
    // j = 32(jt>>1) + 8qd + 4(jt&1) + r due to permuted staging)
    f32x4 sacc[4] = {};
    __builtin_amdgcn_s_setprio(1);
    #pragma unroll
    for (int jt = 0; jt < 4; ++jt)
      #pragma unroll
      for (int kt = 0; kt < 2; ++kt) {
        bf16x8 kf = *(const bf16x8*)&Ks[par][fidx[jt][kt]];
        sacc[jt] = __builtin_amdgcn_mfma_f32_16x16x32_bf16(kf, qf[kt], sacc[jt], 0, 0, 0);
      }
    __builtin_amdgcn_s_setprio(0);

    if (j0 + 63 > qw) {                       // causal mask, diagonal tile only
      const int qg = qw + mi;
      #pragma unroll
      for (int jt = 0; jt < 4; ++jt)
        #pragma unroll
        for (int r = 0; r < 4; ++r) {
          int jg = j0 + ((jt >> 1) << 5) + (qd << 3) + ((jt & 1) << 2) + r;
          if (jg > qg) sacc[jt][r] = -1e30f;
        }
    }

    // p = exp2(s); per-lane partial l; pack: lane holds keys 32kt+8qd+0..7
    // = the K=32 B-operand fragment, keys in natural order.
    uint32_t pu[4][2];
    #pragma unroll
    for (int jt = 0; jt < 4; ++jt) {
      float p0 = fexp2(sacc[jt][0]);
      float p1 = fexp2(sacc[jt][1]);
      float p2 = fexp2(sacc[jt][2]);
      float p3 = fexp2(sacc[jt][3]);
      lst += (p0 + p1) + (p2 + p3);
      pu[jt][0] = pktr(p0, p1);
      pu[jt][1] = pktr(p2, p3);
    }
    bf16x8 pB[2];
    #pragma unroll
    for (int kt = 0; kt < 2; ++kt) {
      union { uint32_t u[4]; bf16x8 v; } m;
      m.u[0] = pu[2 * kt][0];     m.u[1] = pu[2 * kt][1];
      m.u[2] = pu[2 * kt + 1][0]; m.u[3] = pu[2 * kt + 1][1];
      pB[kt] = m.v;
    }

    // O^T += V^T @ P^T via K=32 MFMA (V b128 reads, same pattern as K reads)
    __builtin_amdgcn_s_setprio(1);
    #pragma unroll
    for (int kt = 0; kt < 2; ++kt)
      #pragma unroll
      for (int dt = 0; dt < 4; ++dt) {
        bf16x8 vf = *(const bf16x8*)&Vs[par][fidx[dt][kt]];
        oacc[dt] = __builtin_amdgcn_mfma_f32_16x16x32_bf16(vf, pB[kt], oacc[dt], 0, 0, 0);
      }
    __builtin_amdgcn_s_setprio(0);
  }

  // epilogue: finish l across quads, normalize, packed uint2 stores
  float l = lst;
  l += __shfl_xor(l, 16);
  l += __shfl_xor(l, 32);
  float inv = __builtin_amdgcn_rcpf(l);
  const int qg = qw + mi;
  bf16* cp = ctx + bTD + (size_t)qg * D_ + h * HD_ + qd * 4;
  #pragma unroll
  for (int dt = 0; dt < 4; ++dt) {
    union { bf16 o[4]; uint2 u; } pko;
    #pragma unroll
    for (int r = 0; r < 4; ++r) pko.o[r] = __float2bfloat16(oacc[dt][r] * inv);
    *(uint2*)(cp + dt * 16) = pko.u;
  }
}

// ---------------- launch ----------------
extern "C" void kernel_launch(void* const* d_in, const int* in_sizes, int n_in,
                              void* d_out, int out_size, void* d_ws, size_t ws_size,
                              hipStream_t stream) {
  const float* x  = (const float*)d_in[0];
  const float* Wq = (const float*)d_in[1];
  const float* Wk = (const float*)d_in[2];
  const float* Wv = (const float*)d_in[3];
  const float* Wo = (const float*)d_in[4];
  const float* bo = (const float*)d_in[5];
  float* out = (float*)d_out;

  char* ws = (char*)d_ws;
  const size_t SZ  = (size_t)M_ * D_ * 2;
  const size_t WSZ = (size_t)D_ * D_ * 2;
  bf16* xb   = (bf16*)(ws);                 // [M, D]
  bf16* Qb   = (bf16*)(ws + 1 * SZ);        // [B,T,D]
  bf16* Kb   = (bf16*)(ws + 2 * SZ);        // [B,T,D], pre-scaled by SCL
  bf16* Vtg  = (bf16*)(ws + 3 * SZ);        // [B][D][T]
  bf16* ctxb = (bf16*)(ws + 4 * SZ);        // [B,T,D]
  bf16* Wqb  = (bf16*)(ws + 5 * SZ);
  bf16* Wkb  = (bf16*)(ws + 5 * SZ + 1 * WSZ);
  bf16* Wvb  = (bf16*)(ws + 5 * SZ + 2 * WSZ);
  bf16* Wob  = (bf16*)(ws + 5 * SZ + 3 * WSZ);

  cvt_all<<<6144 + 4 * 576, 256, 0, stream>>>(x, Wq, Wk, Wv, Wo, xb, Wqb, Wkb, Wvb, Wob);

  gemm_qkv<<<1152, 256, 0, stream>>>(xb, Wqb, Wkb, Wvb, Qb, Kb, Vtg);

  flash_attn<<<(T_ / 64) * B_ * H_, 256, 0, stream>>>(Qb, Kb, Vtg, ctxb);

  gemm_out<<<768, 256, 0, stream>>>(ctxb, Wob, out, bo);
}